// Round 9
// baseline (707.910 us; speedup 1.0000x reference)
//
#include <hip/hip_runtime.h>

typedef __attribute__((ext_vector_type(4))) int   int4v;
typedef __attribute__((ext_vector_type(4))) float float4v;

// XOR swizzle of the 16B slot within a 64B K-row (round-0 proven layout).
__device__ __forceinline__ int swz(int row, int slot) {
    return slot ^ ((row ^ (row >> 2)) & 3);
}

// Fake-quant grid index, bit-exact vs reference (round-3 validated).
__device__ __forceinline__ int4v quant4(float4v v, float lo, float up,
                                        float scale, float inv) {
    float t0 = fminf(fmaxf(v[0], lo), up) - lo;
    float t1 = fminf(fmaxf(v[1], lo), up) - lo;
    float t2 = fminf(fmaxf(v[2], lo), up) - lo;
    float t3 = fminf(fmaxf(v[3], lo), up) - lo;
    float m0 = t0 * inv, m1 = t1 * inv, m2 = t2 * inv, m3 = t3 * inv;
    float r0 = rintf(m0), r1 = rintf(m1), r2 = rintf(m2), r3 = rintf(m3);
    float d0 = fabsf(fabsf(m0 - r0) - 0.5f);
    float d1 = fabsf(fabsf(m1 - r1) - 0.5f);
    float d2 = fabsf(fabsf(m2 - r2) - 0.5f);
    float d3 = fabsf(fabsf(m3 - r3) - 0.5f);
    if (fminf(fminf(d0, d1), fminf(d2, d3)) < 1e-4f) {   // rare tie-suspect
        r0 = rintf(t0 / scale); r1 = rintf(t1 / scale);
        r2 = rintf(t2 / scale); r3 = rintf(t3 / scale);
    }
    int4v q = {(int)r0, (int)r1, (int)r2, (int)r3};
    return q;
}

__device__ __forceinline__ unsigned bsum(int p) {
    return ((unsigned)p * 0x01010101u) >> 24;
}

// ---------------- real kernel: round-3 verbatim (98.6 us, absmax 0.875) ----
__global__ __launch_bounds__(256, 4) void qmm_kernel(
    const float* __restrict__ A, const float* __restrict__ B,
    const float* __restrict__ aLo, const float* __restrict__ aUp,
    const float* __restrict__ bLo, const float* __restrict__ bUp,
    float* __restrict__ Out)
{
    __shared__ int   qA[256 * 16];
    __shared__ int   qB[256 * 16];
    __shared__ float RAf[256];
    __shared__ float CBf[256];

    const int tid = threadIdx.x;
    const int b   = blockIdx.x;

    const float lA = aLo[0], uA = aUp[0];
    const float lB = bLo[0], uB = bUp[0];
    const float sA  = (uA - lA) / 15.0f;
    const float sB  = (uB - lB) / 15.0f;
    const float iA  = 1.0f / sA;
    const float iB  = 1.0f / sB;
    const float sAB = sA * sB;

    const float4v* A4 = (const float4v*)(A + (size_t)b * 256 * 64);
    const float4v* B4 = (const float4v*)(B + (size_t)b * 64 * 256);
    float* outb = Out + (size_t)b * 256 * 256;

    #pragma unroll
    for (int it = 0; it < 16; ++it) {
        int f = it * 256 + tid;
        float4v v = A4[f];
        int4v q = quant4(v, lA, uA, sA, iA);
        int p  = q[0] | (q[1] << 8) | (q[2] << 16) | (q[3] << 24);
        int row = f >> 4, chunk = f & 15;
        qA[row * 16 + swz(row, chunk >> 2) * 4 + (chunk & 3)] = p;
    }

    const int u  = tid & 63;
    const int kg = tid >> 6;
    #pragma unroll
    for (int kb = 0; kb < 4; ++kb) {
        int k0 = kb * 16 + kg * 4;
        int4v q0 = quant4(B4[(size_t)(k0 + 0) * 64 + u], lB, uB, sB, iB);
        int4v q1 = quant4(B4[(size_t)(k0 + 1) * 64 + u], lB, uB, sB, iB);
        int4v q2 = quant4(B4[(size_t)(k0 + 2) * 64 + u], lB, uB, sB, iB);
        int4v q3 = quant4(B4[(size_t)(k0 + 3) * 64 + u], lB, uB, sB, iB);
        #pragma unroll
        for (int c = 0; c < 4; ++c) {
            int col = u * 4 + c;
            int p = q0[c] | (q1[c] << 8) | (q2[c] << 16) | (q3[c] << 24);
            qB[col * 16 + swz(col, kb) * 4 + kg] = p;
        }
    }

    __syncthreads();

    {
        unsigned sa = 0, sb = 0;
        #pragma unroll
        for (int j = 0; j < 16; ++j) {
            unsigned pa = (unsigned)qA[tid * 16 + swz(tid, j >> 2) * 4 + (j & 3)];
            unsigned pb = (unsigned)qB[tid * 16 + swz(tid, j >> 2) * 4 + (j & 3)];
            sa += bsum(pa);
            sb += bsum(pb);
        }
        float c32 = 32.0f * lA * lB;
        RAf[tid] = sA * lB * (float)sa + c32;
        CBf[tid] = lA * sB * (float)sb + c32;
    }
    __syncthreads();

    const int wave = tid >> 6, lane = tid & 63;
    const int lr = lane & 15;
    const int lk = lane >> 4;

    int4v afrag[4];
    #pragma unroll
    for (int rt = 0; rt < 4; ++rt) {
        int row = wave * 64 + rt * 16 + lr;
        afrag[rt] = *(const int4v*)&qA[row * 16 + swz(row, lk) * 4];
    }

    #pragma unroll 4
    for (int ct = 0; ct < 16; ++ct) {
        int col = ct * 16 + lr;
        int4v bfrag = *(const int4v*)&qB[col * 16 + swz(col, lk) * 4];
        float cb = CBf[col];
        #pragma unroll
        for (int rt = 0; rt < 4; ++rt) {
            int4v acc = {0, 0, 0, 0};
            acc = __builtin_amdgcn_mfma_i32_16x16x64_i8(afrag[rt], bfrag, acc, 0, 0, 0);
            int orow = wave * 64 + rt * 16 + lk * 4;
            #pragma unroll
            for (int r = 0; r < 4; ++r) {
                outb[(size_t)(orow + r) * 256 + col] =
                    sAB * (float)acc[r] + RAf[orow + r] + cb;
            }
        }
    }
}

// ============ 1-GiB phase-replica probes (each >165us -> rocprof top-5) =====

// pread: 16 back-to-back EXACT stage-A replicas per block (load+quant+LDS+bar).
// 1024 blocks x 1 MiB = 1 GiB read.
__global__ __launch_bounds__(256, 4) void pread_kernel(
    const float4v* __restrict__ src, unsigned* __restrict__ sink)
{
    __shared__ int qA[256 * 16];
    const int tid = threadIdx.x;
    const float lo = -2.5f, up = 2.5f;
    const float sc = (up - lo) / 15.0f, inv = 1.0f / sc;
    const float4v* base = src + (size_t)blockIdx.x * 65536;

    for (int j = 0; j < 16; ++j) {
        #pragma unroll
        for (int it = 0; it < 16; ++it) {
            int f = it * 256 + tid;
            float4v v = base[j * 4096 + f];
            int4v q = quant4(v, lo, up, sc, inv);
            int p  = q[0] | (q[1] << 8) | (q[2] << 16) | (q[3] << 24);
            int row = f >> 4, chunk = f & 15;
            qA[row * 16 + swz(row, chunk >> 2) * 4 + (chunk & 3)] = p;
        }
        __syncthreads();
    }
    sink[(size_t)blockIdx.x * 256 + tid] = (unsigned)qA[tid * 16];
}

// pwdense: contiguous dwordx4 streaming stores, same 1024x256 geometry.
// 1024 blocks x 1 MiB = 1 GiB written.
__global__ __launch_bounds__(256, 4) void pwdense_kernel(float4v* __restrict__ dst)
{
    const float4v v = {1.0f, 2.0f, 3.0f, 4.0f};
    float4v* base = dst + (size_t)blockIdx.x * 65536 + threadIdx.x;
    for (int it = 0; it < 256; ++it)
        base[(size_t)it * 256] = v;
}

// pwscat: EXACT r3-epilogue store pattern (scalar dword, 64B segs, 1KB stride),
// values fabricated. 4 reps of a 256KB tile per block = 1 GiB total.
__global__ __launch_bounds__(256, 4) void pwscat_kernel(float* __restrict__ dst)
{
    const int tid = threadIdx.x, wave = tid >> 6, lane = tid & 63;
    const int lr = lane & 15, lk = lane >> 4;
    float* blk = dst + (size_t)blockIdx.x * 262144;

    for (int rep = 0; rep < 4; ++rep) {
        float* o = blk + rep * 65536;
        float vb = (float)(tid + rep);
        #pragma unroll 4
        for (int ct = 0; ct < 16; ++ct) {
            int col = ct * 16 + lr;
            #pragma unroll
            for (int rt = 0; rt < 4; ++rt) {
                int orow = wave * 64 + rt * 16 + lk * 4;
                #pragma unroll
                for (int r = 0; r < 4; ++r)
                    o[(size_t)(orow + r) * 256 + col] = vb + (float)(orow + r - col);
            }
        }
    }
}

extern "C" void kernel_launch(void* const* d_in, const int* in_sizes, int n_in,
                              void* d_out, int out_size, void* d_ws, size_t ws_size,
                              hipStream_t stream) {
    const float* A   = (const float*)d_in[0];
    const float* B   = (const float*)d_in[1];
    const float* aLo = (const float*)d_in[2];
    const float* aUp = (const float*)d_in[3];
    const float* bLo = (const float*)d_in[4];
    const float* bUp = (const float*)d_in[5];
    float* Out = (float*)d_out;

    int batches = in_sizes[0] / (256 * 64);   // 128*8 = 1024
    qmm_kernel<<<batches, 256, 0, stream>>>(A, B, aLo, aUp, bLo, bUp, Out);

    // ---- measurement round: three 1-GiB phase replicas on d_ws ----
    if (ws_size >= ((size_t)1 << 30)) {
        pread_kernel <<<1024, 256, 0, stream>>>((const float4v*)d_ws,
                                                (unsigned*)d_ws);
        pwdense_kernel<<<1024, 256, 0, stream>>>((float4v*)d_ws);
        pwscat_kernel <<<1024, 256, 0, stream>>>((float*)d_ws);
    }
}

// Round 10
// 102.681 us; speedup vs baseline: 6.8942x; 6.8942x over previous
//
#include <hip/hip_runtime.h>

typedef __attribute__((ext_vector_type(4))) int   int4v;
typedef __attribute__((ext_vector_type(4))) float float4v;

// XOR swizzle of the 16B slot within a 64B K-row (round-0 proven layout).
__device__ __forceinline__ int swz(int row, int slot) {
    return slot ^ ((row ^ (row >> 2)) & 3);
}

// Pure-division fake-quant (bit-exact vs reference by construction; BRANCHLESS
// so the unrolled load/quant loop can be software-pipelined by the scheduler).
__device__ __forceinline__ int4v quant4(float4v v, float lo, float up, float sc) {
    int4v q;
    #pragma unroll
    for (int i = 0; i < 4; ++i) {
        float xc = fminf(fmaxf(v[i], lo), up);
        q[i] = (int)rintf((xc - lo) / sc);
    }
    return q;
}

__device__ __forceinline__ unsigned bsum(int p) {        // sum of 4 bytes (<=15 each)
    return ((unsigned)p * 0x01010101u) >> 24;
}

__global__ __launch_bounds__(256, 4) void qmm_kernel(
    const float* __restrict__ A, const float* __restrict__ B,
    const float* __restrict__ aLo, const float* __restrict__ aUp,
    const float* __restrict__ bLo, const float* __restrict__ bUp,
    float* __restrict__ Out)
{
    __shared__ int   qA[256 * 16];
    __shared__ int   qB[256 * 16];
    __shared__ float RAf[256];
    __shared__ float CBf[256];

    const int tid = threadIdx.x;
    const int b   = blockIdx.x;

    const float lA = aLo[0], uA = aUp[0];
    const float lB = bLo[0], uB = bUp[0];
    const float sA  = (uA - lA) / 15.0f;
    const float sB  = (uB - lB) / 15.0f;
    const float sAB = sA * sB;

    const float4v* A4 = (const float4v*)(A + (size_t)b * 256 * 64);
    const float4v* B4 = (const float4v*)(B + (size_t)b * 64 * 256);
    float* outb = Out + (size_t)b * 256 * 256;

    // ---- stage A: issue ALL 16 coalesced float4 loads first (16 in flight),
    //      then quantize+pack+LDS. Branchless body -> pipelined schedule.
    {
        float4v va[16];
        #pragma unroll
        for (int it = 0; it < 16; ++it)
            va[it] = A4[it * 256 + tid];
        #pragma unroll
        for (int it = 0; it < 16; ++it) {
            int f = it * 256 + tid;
            int4v q = quant4(va[it], lA, uA, sA);
            int p  = q[0] | (q[1] << 8) | (q[2] << 16) | (q[3] << 24);
            int row = f >> 4, chunk = f & 15;
            qA[row * 16 + swz(row, chunk >> 2) * 4 + (chunk & 3)] = p;
        }
    }

    // ---- stage B: same pattern — 16 loads up front, then transpose in regs.
    const int u  = tid & 63;   // column group: cols 4u..4u+3
    const int kg = tid >> 6;   // wave id -> 4-byte offset inside 16B k-slot
    {
        float4v vb[16];
        #pragma unroll
        for (int kb = 0; kb < 4; ++kb)
            #pragma unroll
            for (int r = 0; r < 4; ++r)
                vb[kb * 4 + r] = B4[(size_t)(kb * 16 + kg * 4 + r) * 64 + u];

        #pragma unroll
        for (int kb = 0; kb < 4; ++kb) {
            int4v q0 = quant4(vb[kb * 4 + 0], lB, uB, sB);
            int4v q1 = quant4(vb[kb * 4 + 1], lB, uB, sB);
            int4v q2 = quant4(vb[kb * 4 + 2], lB, uB, sB);
            int4v q3 = quant4(vb[kb * 4 + 3], lB, uB, sB);
            #pragma unroll
            for (int c = 0; c < 4; ++c) {
                int col = u * 4 + c;
                int p = q0[c] | (q1[c] << 8) | (q2[c] << 16) | (q3[c] << 24);
                qB[col * 16 + swz(col, kb) * 4 + kg] = p;
            }
        }
    }

    __syncthreads();

    // ---- row sums of qA / col sums of B (rows of qB), byte-sum trick ----
    {
        unsigned sa = 0, sb = 0;
        #pragma unroll
        for (int j = 0; j < 16; ++j) {
            unsigned pa = (unsigned)qA[tid * 16 + swz(tid, j >> 2) * 4 + (j & 3)];
            unsigned pb = (unsigned)qB[tid * 16 + swz(tid, j >> 2) * 4 + (j & 3)];
            sa += bsum(pa);
            sb += bsum(pb);
        }
        float c32 = 32.0f * lA * lB;
        RAf[tid] = sA * lB * (float)sa + c32;
        CBf[tid] = lA * sB * (float)sb + c32;
    }
    __syncthreads();

    // ---- compute + proven scalar-store epilogue (r3 verbatim) ----
    const int wave = tid >> 6, lane = tid & 63;
    const int lr = lane & 15;
    const int lk = lane >> 4;

    int4v afrag[4];
    #pragma unroll
    for (int rt = 0; rt < 4; ++rt) {
        int row = wave * 64 + rt * 16 + lr;
        afrag[rt] = *(const int4v*)&qA[row * 16 + swz(row, lk) * 4];
    }

    #pragma unroll 4
    for (int ct = 0; ct < 16; ++ct) {
        int col = ct * 16 + lr;
        int4v bfrag = *(const int4v*)&qB[col * 16 + swz(col, lk) * 4];
        float cb = CBf[col];
        #pragma unroll
        for (int rt = 0; rt < 4; ++rt) {
            int4v acc = {0, 0, 0, 0};
            acc = __builtin_amdgcn_mfma_i32_16x16x64_i8(afrag[rt], bfrag, acc, 0, 0, 0);
            int orow = wave * 64 + rt * 16 + lk * 4;
            #pragma unroll
            for (int r = 0; r < 4; ++r) {
                outb[(size_t)(orow + r) * 256 + col] =
                    sAB * (float)acc[r] + RAf[orow + r] + cb;
            }
        }
    }
}

extern "C" void kernel_launch(void* const* d_in, const int* in_sizes, int n_in,
                              void* d_out, int out_size, void* d_ws, size_t ws_size,
                              hipStream_t stream) {
    const float* A   = (const float*)d_in[0];
    const float* B   = (const float*)d_in[1];
    const float* aLo = (const float*)d_in[2];
    const float* aUp = (const float*)d_in[3];
    const float* bLo = (const float*)d_in[4];
    const float* bUp = (const float*)d_in[5];
    float* Out = (float*)d_out;

    int batches = in_sizes[0] / (256 * 64);   // 128*8 = 1024
    qmm_kernel<<<batches, 256, 0, stream>>>(A, B, aLo, aUp, bLo, bUp, Out);
}